// Round 1
// baseline (656.617 us; speedup 1.0000x reference)
//
#include <hip/hip_runtime.h>
#include <stdint.h>

#define B_    2
#define T_    2048
#define DIM_  2048
#define H_    16
#define DC_   512
#define DCQ_  1536
#define NROWS (B_*T_)   // 4096

typedef unsigned short u16;
typedef __attribute__((ext_vector_type(8))) __bf16 bf16x8;
typedef __attribute__((ext_vector_type(4))) float  f32x4;
typedef __attribute__((ext_vector_type(8))) unsigned short u16x8;
typedef __attribute__((ext_vector_type(4))) float  f4v;

__device__ __forceinline__ u16 f2bf(float f){
  unsigned u = __float_as_uint(f);
  u += 0x7FFFu + ((u >> 16) & 1u);   // round-to-nearest-even (no NaN inputs expected)
  return (u16)(u >> 16);
}
__device__ __forceinline__ float bf2f(u16 h){ return __uint_as_float(((unsigned)h) << 16); }

// async global->LDS, 16B per lane. LDS base must be wave-uniform (dest = base + lane*16).
// AS casts via uintptr_t (CK's amd_direct_load pattern): flat LDS addr low 32 bits = LDS offset.
__device__ __forceinline__ void gld_lds16(const void* g, void* l){
  auto gp = reinterpret_cast<__attribute__((address_space(1))) unsigned int*>(
      reinterpret_cast<uintptr_t>(g));
  auto lp = reinterpret_cast<__attribute__((address_space(3))) unsigned int*>(
      reinterpret_cast<uintptr_t>(l));
  __builtin_amdgcn_global_load_lds(gp, lp, 16, 0, 0);
}

__device__ __forceinline__ f32x4 mfma16(bf16x8 a, bf16x8 b, f32x4 c){
  return __builtin_amdgcn_mfma_f32_16x16x32_bf16(a, b, c, 0, 0, 0);
}

// ---------------- dtype detect: cos[0,0]==1.0 -> bf16 u16[0]=0x3F80, fp32 u16[0]=0x0000
__global__ void k_detect(const u16* cosr, int* flag){
  if (threadIdx.x == 0) *flag = (cosr[0] == (u16)0x3F80u) ? 1 : 0;
}

// ---------------- convert (copy-or-downcast) to bf16, 4 elems/thread
__global__ void k_conv(const void* __restrict__ src, u16* __restrict__ dst, int n4, const int* flag){
  int id = blockIdx.x * 256 + threadIdx.x;
  if (id >= n4) return;
  if (*flag){
    reinterpret_cast<uint2*>(dst)[id] = reinterpret_cast<const uint2*>(src)[id];
  } else {
    f4v v = reinterpret_cast<const f4v*>(src)[id];
    unsigned lo = (unsigned)f2bf(v.x) | ((unsigned)f2bf(v.y) << 16);
    unsigned hi = (unsigned)f2bf(v.z) | ((unsigned)f2bf(v.w) << 16);
    reinterpret_cast<uint2*>(dst)[id] = make_uint2(lo, hi);
  }
}

// ---------------- transpose + convert: src (R x C) -> dst (C x R) bf16. R,C multiples of 64.
__global__ void k_transpose(const void* __restrict__ src, u16* __restrict__ dst,
                            int R, int C, const int* flag){
  __shared__ u16 tile[64][72];            // +8 pad: conflict-free both phases
  const int r0 = blockIdx.y << 6, c0 = blockIdx.x << 6;
  const int tid = threadIdx.x;
  const int f = *flag;
  #pragma unroll
  for (int i = 0; i < 2; ++i){
    int task = (i << 8) + tid;            // 0..511
    int r = task >> 3, c8 = (task & 7) << 3;
    if (f){
      const u16* p = (const u16*)src + (size_t)(r0 + r) * C + c0 + c8;
      u16x8 v = *reinterpret_cast<const u16x8*>(p);
      #pragma unroll
      for (int j = 0; j < 8; ++j) tile[r][c8 + j] = v[j];
    } else {
      const float* p = (const float*)src + (size_t)(r0 + r) * C + c0 + c8;
      f4v a = reinterpret_cast<const f4v*>(p)[0];
      f4v b = reinterpret_cast<const f4v*>(p)[1];
      tile[r][c8+0]=f2bf(a.x); tile[r][c8+1]=f2bf(a.y); tile[r][c8+2]=f2bf(a.z); tile[r][c8+3]=f2bf(a.w);
      tile[r][c8+4]=f2bf(b.x); tile[r][c8+5]=f2bf(b.y); tile[r][c8+6]=f2bf(b.z); tile[r][c8+7]=f2bf(b.w);
    }
  }
  __syncthreads();
  #pragma unroll
  for (int i = 0; i < 2; ++i){
    int task = (i << 8) + tid;
    int rr = task >> 3, cc8 = (task & 7) << 3;
    u16x8 v;
    #pragma unroll
    for (int j = 0; j < 8; ++j) v[j] = tile[cc8 + j][rr];
    *reinterpret_cast<u16x8*>(dst + (size_t)(c0 + rr) * R + r0 + cc8) = v;
  }
}

// ---------------- GEMM: C(MxN) = A(MxK, row stride lda) * Bt(NxK row-major)  [bf16 in, fp32 acc]
// 128x128 tile, BK=64, 4 waves in 2x2, 4x4 16x16x32 frags/wave. M%128==0, N%128==0, K%64==0.
__global__ __launch_bounds__(256) void k_gemm(const u16* __restrict__ A, int lda,
                                              const u16* __restrict__ Bt,
                                              u16* __restrict__ C, int ldc,
                                              int M, int N, int K,
                                              void* outp, const int* flag){
  __shared__ alignas(16) u16 As[128 * 64];
  __shared__ alignas(16) u16 Bs[128 * 64];
  const int tid = threadIdx.x;
  const int wid = tid >> 6, lane = tid & 63;
  const int m0 = blockIdx.x << 7, n0 = blockIdx.y << 7;
  const int wr = wid >> 1, wc = wid & 1;
  const int l16 = lane & 15, lk = (lane >> 4) << 3;
  const int srow = tid >> 3, scol = (tid & 7) << 3;   // staging: 8 threads/row, 8 elems each
  f32x4 acc[4][4] = {};
  const int nkt = K >> 6;
  for (int kt = 0; kt < nkt; ++kt){
    const int kb = kt << 6;
    #pragma unroll
    for (int i = 0; i < 4; ++i){
      int r = (i << 5) + srow;
      gld_lds16(A  + (size_t)(m0 + r) * lda + kb + scol, &As[(i << 11) + (wid << 9)]);
      gld_lds16(Bt + (size_t)(n0 + r) * K   + kb + scol, &Bs[(i << 11) + (wid << 9)]);
    }
    __syncthreads();       // drains vmcnt -> staged tiles visible
    #pragma unroll
    for (int ks = 0; ks < 2; ++ks){
      bf16x8 af[4], bfr[4];
      #pragma unroll
      for (int mi = 0; mi < 4; ++mi)
        af[mi] = *reinterpret_cast<const bf16x8*>(&As[((wr << 6) + (mi << 4) + l16) * 64 + (ks << 5) + lk]);
      #pragma unroll
      for (int ni = 0; ni < 4; ++ni)
        bfr[ni] = *reinterpret_cast<const bf16x8*>(&Bs[((wc << 6) + (ni << 4) + l16) * 64 + (ks << 5) + lk]);
      #pragma unroll
      for (int mi = 0; mi < 4; ++mi)
        #pragma unroll
        for (int ni = 0; ni < 4; ++ni)
          acc[mi][ni] = mfma16(af[mi], bfr[ni], acc[mi][ni]);
    }
    __syncthreads();       // all reads done before next stage overwrites
  }
  const int r4 = (lane >> 4) << 2;
  const int f = flag ? *flag : 1;
  #pragma unroll
  for (int mi = 0; mi < 4; ++mi){
    int row = m0 + (wr << 6) + (mi << 4) + r4;
    #pragma unroll
    for (int ni = 0; ni < 4; ++ni){
      int col = n0 + (wc << 6) + (ni << 4) + l16;
      #pragma unroll
      for (int j = 0; j < 4; ++j){
        float v = acc[mi][ni][j];
        if (outp){
          if (f) ((u16*)outp)[(size_t)(row + j) * ldc + col] = f2bf(v);
          else   ((float*)outp)[(size_t)(row + j) * ldc + col] = v;
        } else {
          C[(size_t)(row + j) * ldc + col] = f2bf(v);
        }
      }
    }
  }
}

// ---------------- RoPE: ropes = c_qr cols 1536..1663 (stride 1664); cols 0-63 k-pre, 64-127 q-pre
__global__ void k_rope(const u16* __restrict__ ropes, const void* __restrict__ cosp,
                       const void* __restrict__ sinp, const int* flag,
                       u16* __restrict__ krope, u16* __restrict__ qrope){
  int id = blockIdx.x * 256 + threadIdx.x;
  if (id >= NROWS * 128) return;
  int row = id >> 7, c = id & 127;
  int t = row & (T_ - 1);
  int d = c & 63, i = d & 31;
  float cs, sn;
  if (*flag){ cs = bf2f(((const u16*)cosp)[t * 32 + i]); sn = bf2f(((const u16*)sinp)[t * 32 + i]); }
  else      { cs = ((const float*)cosp)[t * 32 + i];     sn = ((const float*)sinp)[t * 32 + i]; }
  int base = c & 64;                       // 0 = k part, 64 = q part
  float t1 = bf2f(ropes[(size_t)row * 1664 + base + i]);
  float t2 = bf2f(ropes[(size_t)row * 1664 + base + 32 + i]);
  float v = (d < 32) ? (t1 * cs - t2 * sn) : (t2 * cs + t1 * sn);
  ((c < 64) ? krope : qrope)[(size_t)row * 64 + d] = f2bf(v);
}

// ---------------- causal flash attention. Block = (b,h,64-row Q tile), 4 waves x 16 q-rows.
__global__ __launch_bounds__(256) void k_attn(const u16* __restrict__ qdec,   // stride 2048
                                              const u16* __restrict__ kdec,   // stride 4096
                                              const u16* __restrict__ vdec,   // stride 4096
                                              const u16* __restrict__ krope,  // stride 64
                                              const u16* __restrict__ qrope,  // stride 64
                                              u16* __restrict__ aout){        // stride 2048
  __shared__ alignas(16) u16 Vt[128 * 64];       // [d][kv]
  __shared__ alignas(16) u16 Pl[4][16 * 64];     // per-wave [qrow][kv]
  const int tid = threadIdx.x, wid = tid >> 6, lane = tid & 63;
  const int l16 = lane & 15, lk = (lane >> 4) << 3, r4 = (lane >> 4) << 2;
  const int qt = blockIdx.x, bh = blockIdx.y;
  const int b = bh >> 4, h = bh & 15;
  const int q0 = qt << 6;
  const int qrow = q0 + (wid << 4) + l16;
  const size_t grow = (size_t)(b * T_ + qrow);
  bf16x8 qf[4];
  #pragma unroll
  for (int ks = 0; ks < 4; ++ks){
    int d = (ks << 5) + lk;
    const u16* src = (d < 64) ? (qdec + grow * 2048 + h * 128 + d)
                              : (qrope + grow * 64 + (d - 64));
    qf[ks] = *reinterpret_cast<const bf16x8*>(src);
  }
  f32x4 o[8] = {};
  float mrow[4] = {-3e38f, -3e38f, -3e38f, -3e38f};
  float lrow[4] = {0.f, 0.f, 0.f, 0.f};
  const float scl = 0.08838834764831845f;   // 1/sqrt(128)
  const int nkv = qt + 1;
  u16* pw = &Pl[wid][0];
  for (int kv = 0; kv < nkv; ++kv){
    const int k0 = kv << 6;
    __syncthreads();                        // prev PV reads done before overwrite
    // stage V tile transposed: Vt[d][kv]
    #pragma unroll
    for (int i = 0; i < 4; ++i){
      int task = (i << 8) + tid;            // 0..1023
      int r = task >> 4, dc = (task & 15) << 3;
      const u16* vp = vdec + (size_t)(b * T_ + k0 + r) * 4096 + h * 128 + dc;
      u16x8 v = *reinterpret_cast<const u16x8*>(vp);
      #pragma unroll
      for (int j = 0; j < 8; ++j) Vt[(dc + j) * 64 + r] = v[j];
    }
    // S = Q K^T (K frags straight from global: L2-resident per head)
    f32x4 s[4] = {};
    #pragma unroll
    for (int ks = 0; ks < 4; ++ks){
      int d = (ks << 5) + lk;
      #pragma unroll
      for (int n = 0; n < 4; ++n){
        int krw = k0 + (n << 4) + l16;
        const u16* kp = (d < 64) ? (kdec + (size_t)(b * T_ + krw) * 4096 + h * 128 + d)
                                 : (krope + (size_t)(b * T_ + krw) * 64 + (d - 64));
        bf16x8 kf = *reinterpret_cast<const bf16x8*>(kp);
        s[n] = mfma16(qf[ks], kf, s[n]);
      }
    }
    // online softmax (rows r4+j per lane group; 16-lane shfl reduce)
    #pragma unroll
    for (int j = 0; j < 4; ++j){
      int tq = q0 + (wid << 4) + r4 + j;
      float mx = -3e38f;
      #pragma unroll
      for (int n = 0; n < 4; ++n){
        int tk = k0 + (n << 4) + l16;
        float sv = s[n][j] * scl;
        sv = (tk <= tq) ? sv : -3e38f;
        s[n][j] = sv;
        mx = fmaxf(mx, sv);
      }
      mx = fmaxf(mx, __shfl_xor(mx, 1));
      mx = fmaxf(mx, __shfl_xor(mx, 2));
      mx = fmaxf(mx, __shfl_xor(mx, 4));
      mx = fmaxf(mx, __shfl_xor(mx, 8));
      float mnew = fmaxf(mrow[j], mx);
      float alpha = __expf(mrow[j] - mnew);
      float rs = 0.f;
      #pragma unroll
      for (int n = 0; n < 4; ++n){
        float p = __expf(s[n][j] - mnew);
        s[n][j] = p;
        rs += p;
      }
      rs += __shfl_xor(rs, 1); rs += __shfl_xor(rs, 2);
      rs += __shfl_xor(rs, 4); rs += __shfl_xor(rs, 8);
      mrow[j] = mnew;
      lrow[j] = lrow[j] * alpha + rs;
      #pragma unroll
      for (int db = 0; db < 8; ++db) o[db][j] *= alpha;
    }
    // P -> LDS (bf16) to reach MFMA-A layout
    #pragma unroll
    for (int n = 0; n < 4; ++n)
      #pragma unroll
      for (int j = 0; j < 4; ++j)
        pw[(r4 + j) * 64 + (n << 4) + l16] = f2bf(s[n][j]);
    __syncthreads();                        // Vt + Pl visible
    // O += P V
    #pragma unroll
    for (int ks2 = 0; ks2 < 2; ++ks2){
      bf16x8 pa = *reinterpret_cast<const bf16x8*>(&pw[l16 * 64 + (ks2 << 5) + lk]);
      #pragma unroll
      for (int db = 0; db < 8; ++db){
        bf16x8 vb = *reinterpret_cast<const bf16x8*>(&Vt[((db << 4) + l16) * 64 + (ks2 << 5) + lk]);
        o[db] = mfma16(pa, vb, o[db]);
      }
    }
  }
  #pragma unroll
  for (int db = 0; db < 8; ++db){
    int d = (db << 4) + l16;
    #pragma unroll
    for (int j = 0; j < 4; ++j){
      int tq = q0 + (wid << 4) + r4 + j;
      aout[(size_t)(b * T_ + tq) * 2048 + h * 128 + d] = f2bf(o[db][j] / lrow[j]);
    }
  }
}

extern "C" void kernel_launch(void* const* d_in, const int* in_sizes, int n_in,
                              void* d_out, int out_size, void* d_ws, size_t ws_size,
                              hipStream_t stream){
  const void* x       = d_in[0];
  const void* cosp    = d_in[1];
  const void* sinp    = d_in[2];
  const void* w_kv    = d_in[3];
  const void* w_kdec  = d_in[4];
  const void* w_vdec  = d_in[5];
  const void* w_qc    = d_in[6];
  const void* w_qdec  = d_in[7];
  const void* w_krope = d_in[8];
  const void* w_qrope = d_in[9];
  const void* w_o     = d_in[10];

  char* ws = (char*)d_ws;
  size_t off = 0;
  auto alloc = [&](size_t bytes){ void* p = ws + off; off += (bytes + 255) & ~(size_t)255; return p; };
  int* flag     = (int*)alloc(256);
  u16* x_bf     = (u16*)alloc((size_t)NROWS * DIM_ * 2);
  u16* w_kvT    = (u16*)alloc((size_t)DC_ * DIM_ * 2);       // (512 x 2048)
  u16* w_kvdecT = (u16*)alloc((size_t)4096 * DC_ * 2);       // [kdecT; vdecT] (4096 x 512)
  u16* w_qcrT   = (u16*)alloc((size_t)1664 * DIM_ * 2);      // [qcT; kropeT; qropeT] (1664 x 2048)
  u16* w_qdecT  = (u16*)alloc((size_t)DIM_ * DCQ_ * 2);      // (2048 x 1536)
  u16* w_oT     = (u16*)alloc((size_t)DIM_ * DIM_ * 2);      // (2048 x 2048)
  u16* c_kv     = (u16*)alloc((size_t)NROWS * DC_ * 2);
  u16* c_qr     = (u16*)alloc((size_t)NROWS * 1664 * 2);     // cols 0-1535 c_q, 1536-1663 rope-pre
  u16* qdec     = (u16*)alloc((size_t)NROWS * DIM_ * 2);
  u16* kvdec    = (u16*)alloc((size_t)NROWS * 4096 * 2);     // cols 0-2047 k, 2048-4095 v
  u16* krope    = (u16*)alloc((size_t)NROWS * 64 * 2);
  u16* qrope    = (u16*)alloc((size_t)NROWS * 64 * 2);
  u16* aout     = (u16*)alloc((size_t)NROWS * DIM_ * 2);
  (void)in_sizes; (void)n_in; (void)out_size; (void)ws_size;

  hipLaunchKernelGGL(k_detect, dim3(1), dim3(64), 0, stream, (const u16*)cosp, flag);

  int n4 = NROWS * DIM_ / 4;
  hipLaunchKernelGGL(k_conv, dim3((n4 + 255) / 256), dim3(256), 0, stream, x, x_bf, n4, flag);

  // transposes: src (R x C) -> dst (C x R), grid (C/64, R/64)
  hipLaunchKernelGGL(k_transpose, dim3(DC_/64,  DIM_/64), dim3(256), 0, stream, w_kv,    w_kvT,                          DIM_, DC_,  flag);
  hipLaunchKernelGGL(k_transpose, dim3(DIM_/64, DC_/64),  dim3(256), 0, stream, w_kdec,  w_kvdecT,                       DC_,  DIM_, flag);
  hipLaunchKernelGGL(k_transpose, dim3(DIM_/64, DC_/64),  dim3(256), 0, stream, w_vdec,  w_kvdecT + (size_t)2048 * DC_,  DC_,  DIM_, flag);
  hipLaunchKernelGGL(k_transpose, dim3(DCQ_/64, DIM_/64), dim3(256), 0, stream, w_qc,    w_qcrT,                         DIM_, DCQ_, flag);
  hipLaunchKernelGGL(k_transpose, dim3(1,       DIM_/64), dim3(256), 0, stream, w_krope, w_qcrT + (size_t)1536 * DIM_,   DIM_, 64,   flag);
  hipLaunchKernelGGL(k_transpose, dim3(1,       DIM_/64), dim3(256), 0, stream, w_qrope, w_qcrT + (size_t)1600 * DIM_,   DIM_, 64,   flag);
  hipLaunchKernelGGL(k_transpose, dim3(DIM_/64, DCQ_/64), dim3(256), 0, stream, w_qdec,  w_qdecT,                        DCQ_, DIM_, flag);
  hipLaunchKernelGGL(k_transpose, dim3(DIM_/64, DIM_/64), dim3(256), 0, stream, w_o,     w_oT,                           DIM_, DIM_, flag);

  // G1: c_kv = x @ w_kv            (4096 x 512,  K=2048)
  hipLaunchKernelGGL(k_gemm, dim3(NROWS/128, DC_/128), dim3(256), 0, stream,
                     x_bf, DIM_, w_kvT, c_kv, DC_, NROWS, DC_, DIM_, (void*)nullptr, (const int*)nullptr);
  // G2: kvdec = c_kv @ [w_kdec|w_vdec]   (4096 x 4096, K=512)
  hipLaunchKernelGGL(k_gemm, dim3(NROWS/128, 4096/128), dim3(256), 0, stream,
                     c_kv, DC_, w_kvdecT, kvdec, 4096, NROWS, 4096, DC_, (void*)nullptr, (const int*)nullptr);
  // G3: c_qr = x @ [w_qc|w_krope|w_qrope] (4096 x 1664, K=2048)
  hipLaunchKernelGGL(k_gemm, dim3(NROWS/128, 1664/128), dim3(256), 0, stream,
                     x_bf, DIM_, w_qcrT, c_qr, 1664, NROWS, 1664, DIM_, (void*)nullptr, (const int*)nullptr);
  // G4: qdec = c_qr[:, :1536] @ w_qdec   (4096 x 2048, K=1536)
  hipLaunchKernelGGL(k_gemm, dim3(NROWS/128, DIM_/128), dim3(256), 0, stream,
                     c_qr, 1664, w_qdecT, qdec, DIM_, NROWS, DIM_, DCQ_, (void*)nullptr, (const int*)nullptr);
  // RoPE
  hipLaunchKernelGGL(k_rope, dim3(NROWS * 128 / 256), dim3(256), 0, stream,
                     c_qr + 1536, cosp, sinp, flag, krope, qrope);
  // attention
  hipLaunchKernelGGL(k_attn, dim3(T_/64, B_*H_), dim3(256), 0, stream,
                     qdec, kvdec, kvdec + 2048, krope, qrope, aout);
  // G5: out = aout @ w_o  (writes d_out; dtype per flag)
  hipLaunchKernelGGL(k_gemm, dim3(NROWS/128, DIM_/128), dim3(256), 0, stream,
                     aout, DIM_, w_oT, (u16*)nullptr, DIM_, NROWS, DIM_, DIM_, d_out, (const int*)flag);
}

// Round 2
// 429.339 us; speedup vs baseline: 1.5294x; 1.5294x over previous
//
#include <hip/hip_runtime.h>
#include <stdint.h>
#include <math.h>

#define B_    2
#define T_    2048
#define DIM_  2048
#define H_    16
#define DC_   512
#define DCQ_  1536
#define NROWS (B_*T_)   // 4096

typedef unsigned short u16;
typedef __attribute__((ext_vector_type(8))) __bf16 bf16x8;
typedef __attribute__((ext_vector_type(4))) float  f32x4;
typedef __attribute__((ext_vector_type(8))) unsigned short u16x8;
typedef __attribute__((ext_vector_type(4))) float  f4v;

__device__ __forceinline__ u16 f2bf(float f){
  unsigned u = __float_as_uint(f);
  u += 0x7FFFu + ((u >> 16) & 1u);   // RNE
  return (u16)(u >> 16);
}
__device__ __forceinline__ float bf2f(u16 h){ return __uint_as_float(((unsigned)h) << 16); }

// async global->LDS, 16B per lane; LDS dest = wave-uniform base + lane*16.
__device__ __forceinline__ void gld_lds16(const void* g, void* l){
  auto gp = reinterpret_cast<__attribute__((address_space(1))) unsigned int*>(
      reinterpret_cast<uintptr_t>(g));
  auto lp = reinterpret_cast<__attribute__((address_space(3))) unsigned int*>(
      reinterpret_cast<uintptr_t>(l));
  __builtin_amdgcn_global_load_lds(gp, lp, 16, 0, 0);
}

__device__ __forceinline__ f32x4 mfma16(bf16x8 a, bf16x8 b, f32x4 c){
  return __builtin_amdgcn_mfma_f32_16x16x32_bf16(a, b, c, 0, 0, 0);
}

// ---------------- dtype detect: cos[0,0]==1.0 -> bf16 u16[0]=0x3F80, fp32 u16[0]=0x0000
__global__ void k_detect(const u16* cosr, int* flag){
  if (threadIdx.x == 0) *flag = (cosr[0] == (u16)0x3F80u) ? 1 : 0;
}

// ---------------- convert to bf16
__global__ void k_conv(const void* __restrict__ src, u16* __restrict__ dst, int n4, const int* flag){
  int id = blockIdx.x * 256 + threadIdx.x;
  if (id >= n4) return;
  if (*flag){
    reinterpret_cast<uint2*>(dst)[id] = reinterpret_cast<const uint2*>(src)[id];
  } else {
    f4v v = reinterpret_cast<const f4v*>(src)[id];
    unsigned lo = (unsigned)f2bf(v.x) | ((unsigned)f2bf(v.y) << 16);
    unsigned hi = (unsigned)f2bf(v.z) | ((unsigned)f2bf(v.w) << 16);
    reinterpret_cast<uint2*>(dst)[id] = make_uint2(lo, hi);
  }
}

// ---------------- transpose+convert to bf16 with optional column packing.
// Source tile: rows [by*64, +64), cols [bx*cblk, bx*cblk+64).
// Dest: rows bx*64+(0..63) (stride dstStride), cols by*64+(0..63).
__global__ void k_transpose(const void* __restrict__ src, u16* __restrict__ dst,
                            int srcStride, int dstStride, int cblk, const int* flag){
  __shared__ u16 tile[64][72];
  const int r0 = blockIdx.y << 6, c0 = blockIdx.x * cblk;
  const int tid = threadIdx.x;
  const int f = *flag;
  #pragma unroll
  for (int i = 0; i < 2; ++i){
    int task = (i << 8) + tid;
    int r = task >> 3, c8 = (task & 7) << 3;
    if (f){
      const u16* p = (const u16*)src + (size_t)(r0 + r) * srcStride + c0 + c8;
      u16x8 v = *reinterpret_cast<const u16x8*>(p);
      #pragma unroll
      for (int j = 0; j < 8; ++j) tile[r][c8 + j] = v[j];
    } else {
      const float* p = (const float*)src + (size_t)(r0 + r) * srcStride + c0 + c8;
      f4v a = reinterpret_cast<const f4v*>(p)[0];
      f4v b = reinterpret_cast<const f4v*>(p)[1];
      tile[r][c8+0]=f2bf(a.x); tile[r][c8+1]=f2bf(a.y); tile[r][c8+2]=f2bf(a.z); tile[r][c8+3]=f2bf(a.w);
      tile[r][c8+4]=f2bf(b.x); tile[r][c8+5]=f2bf(b.y); tile[r][c8+6]=f2bf(b.z); tile[r][c8+7]=f2bf(b.w);
    }
  }
  __syncthreads();
  #pragma unroll
  for (int i = 0; i < 2; ++i){
    int task = (i << 8) + tid;
    int rr = task >> 3, cc8 = (task & 7) << 3;
    u16x8 v;
    #pragma unroll
    for (int j = 0; j < 8; ++j) v[j] = tile[cc8 + j][rr];
    *reinterpret_cast<u16x8*>(dst + (size_t)((blockIdx.x << 6) + rr) * dstStride + r0 + cc8) = v;
  }
}

// ---------------- build vT[bh][d][t] from kvP cols 1024 + h*128 + d (bf16 only)
__global__ void k_vt(const u16* __restrict__ kvP, u16* __restrict__ vT){
  __shared__ u16 tile[64][72];
  const int t0 = blockIdx.x << 6, d0 = blockIdx.y << 6, bh = blockIdx.z;
  const int b = bh >> 4, h = bh & 15;
  const int tid = threadIdx.x;
  #pragma unroll
  for (int i = 0; i < 2; ++i){
    int task = (i << 8) + tid;
    int r = task >> 3, c8 = (task & 7) << 3;
    const u16* p = kvP + (size_t)(b * T_ + t0 + r) * 3072 + 1024 + h * 128 + d0 + c8;
    u16x8 v = *reinterpret_cast<const u16x8*>(p);
    #pragma unroll
    for (int j = 0; j < 8; ++j) tile[r][c8 + j] = v[j];
  }
  __syncthreads();
  #pragma unroll
  for (int i = 0; i < 2; ++i){
    int task = (i << 8) + tid;
    int rr = task >> 3, cc8 = (task & 7) << 3;
    u16x8 v;
    #pragma unroll
    for (int j = 0; j < 8; ++j) v[j] = tile[cc8 + j][rr];
    *reinterpret_cast<u16x8*>(vT + ((size_t)bh * 128 + d0 + rr) * T_ + t0 + cc8) = v;
  }
}

// ---------------- GEMM: C(MxN) = A(MxK, lda) * Bt(NxK row-major)  [bf16 in, fp32 acc]
__global__ __launch_bounds__(256) void k_gemm(const u16* __restrict__ A, int lda,
                                              const u16* __restrict__ Bt,
                                              u16* __restrict__ C, int ldc,
                                              int M, int N, int K,
                                              void* outp, const int* flag){
  __shared__ alignas(16) u16 As[128 * 64];
  __shared__ alignas(16) u16 Bs[128 * 64];
  const int tid = threadIdx.x;
  const int wid = tid >> 6, lane = tid & 63;
  const int m0 = blockIdx.x << 7, n0 = blockIdx.y << 7;
  const int wr = wid >> 1, wc = wid & 1;
  const int l16 = lane & 15, lk = (lane >> 4) << 3;
  const int srow = tid >> 3, scol = (tid & 7) << 3;
  f32x4 acc[4][4] = {};
  const int nkt = K >> 6;
  for (int kt = 0; kt < nkt; ++kt){
    const int kb = kt << 6;
    #pragma unroll
    for (int i = 0; i < 4; ++i){
      int r = (i << 5) + srow;
      gld_lds16(A  + (size_t)(m0 + r) * lda + kb + scol, &As[(i << 11) + (wid << 9)]);
      gld_lds16(Bt + (size_t)(n0 + r) * K   + kb + scol, &Bs[(i << 11) + (wid << 9)]);
    }
    __syncthreads();
    #pragma unroll
    for (int ks = 0; ks < 2; ++ks){
      bf16x8 af[4], bfr[4];
      #pragma unroll
      for (int mi = 0; mi < 4; ++mi)
        af[mi] = *reinterpret_cast<const bf16x8*>(&As[((wr << 6) + (mi << 4) + l16) * 64 + (ks << 5) + lk]);
      #pragma unroll
      for (int ni = 0; ni < 4; ++ni)
        bfr[ni] = *reinterpret_cast<const bf16x8*>(&Bs[((wc << 6) + (ni << 4) + l16) * 64 + (ks << 5) + lk]);
      #pragma unroll
      for (int mi = 0; mi < 4; ++mi)
        #pragma unroll
        for (int ni = 0; ni < 4; ++ni)
          acc[mi][ni] = mfma16(af[mi], bfr[ni], acc[mi][ni]);
    }
    __syncthreads();
  }
  const int r4 = (lane >> 4) << 2;
  const int f = flag ? *flag : 1;
  #pragma unroll
  for (int mi = 0; mi < 4; ++mi){
    int row = m0 + (wr << 6) + (mi << 4) + r4;
    #pragma unroll
    for (int ni = 0; ni < 4; ++ni){
      int col = n0 + (wc << 6) + (ni << 4) + l16;
      #pragma unroll
      for (int j = 0; j < 4; ++j){
        float v = acc[mi][ni][j];
        if (outp){
          if (f) ((u16*)outp)[(size_t)(row + j) * ldc + col] = f2bf(v);
          else   ((float*)outp)[(size_t)(row + j) * ldc + col] = v;
        } else {
          C[(size_t)(row + j) * ldc + col] = f2bf(v);
        }
      }
    }
  }
}

// ---------------- RoPE from c_qr cols 1536..1663 (stride 1664)
__global__ void k_rope(const u16* __restrict__ ropes, const void* __restrict__ cosp,
                       const void* __restrict__ sinp, const int* flag,
                       u16* __restrict__ krope, u16* __restrict__ qrope){
  int id = blockIdx.x * 256 + threadIdx.x;
  if (id >= NROWS * 128) return;
  int row = id >> 7, c = id & 127;
  int t = row & (T_ - 1);
  int d = c & 63, i = d & 31;
  float cs, sn;
  if (*flag){ cs = bf2f(((const u16*)cosp)[t * 32 + i]); sn = bf2f(((const u16*)sinp)[t * 32 + i]); }
  else      { cs = ((const float*)cosp)[t * 32 + i];     sn = ((const float*)sinp)[t * 32 + i]; }
  int base = c & 64;
  float t1 = bf2f(ropes[(size_t)row * 1664 + base + i]);
  float t2 = bf2f(ropes[(size_t)row * 1664 + base + 32 + i]);
  float v = (d < 32) ? (t1 * cs - t2 * sn) : (t2 * cs + t1 * sn);
  ((c < 64) ? krope : qrope)[(size_t)row * 64 + d] = f2bf(v);
}

// ---------------- causal flash attention.
// Block = (b,h, 128-row Q tile), 4 waves x 32 q-rows. KV tiles of 64.
// LDS (swizzled col ^= (row&7)<<3, staged via pre-swizzled global sources):
//   Ks [64][128] u16 @0      (cols 0-63 kdec-packed, 64-127 krope)
//   Vs [128][64] u16 @8192   (row=d, col=kv; from pre-transposed vT)
//   Ps [32][64]  u16 @16384 + wid*2048 (per-wave)
__global__ __launch_bounds__(256, 2) void k_attn(const u16* __restrict__ qP,
                                                 const u16* __restrict__ kvP,
                                                 const u16* __restrict__ vT,
                                                 const u16* __restrict__ krope,
                                                 const u16* __restrict__ qrope,
                                                 u16* __restrict__ aout){
  __shared__ alignas(16) u16 smem[24576];   // 48 KB
  const int tid = threadIdx.x, wid = tid >> 6, lane = tid & 63;
  const int l16 = lane & 15, g = lane >> 4;
  const int lk = g << 3, r4 = g << 2;
  const int qt = 15 - (int)blockIdx.x;      // LPT: heaviest blocks dispatch first
  const int bh = blockIdx.y, b = bh >> 4, h = bh & 15;
  const int q0 = qt << 7;
  const size_t bT = (size_t)b * T_;
  const int sw = (l16 & 7) << 3;

  bf16x8 qf[2][4];
  #pragma unroll
  for (int rg = 0; rg < 2; ++rg){
    size_t grow = bT + q0 + (wid << 5) + (rg << 4) + l16;
    #pragma unroll
    for (int ks = 0; ks < 4; ++ks){
      int d = (ks << 5) + lk;
      const u16* src = (ks < 2) ? (qP + grow * 1024 + (h << 6) + d)
                                : (qrope + grow * 64 + (d - 64));
      qf[rg][ks] = *reinterpret_cast<const bf16x8*>(src);
    }
  }
  f32x4 o[2][8] = {};
  float m[2][4], l[2][4];
  #pragma unroll
  for (int rg = 0; rg < 2; ++rg)
    #pragma unroll
    for (int j = 0; j < 4; ++j){ m[rg][j] = -3e38f; l[rg][j] = 0.f; }
  const float sc2 = 0.08838834764831845f * 1.4426950408889634f;   // 1/sqrt(128) * log2(e)
  const u16* kvPb = kvP + bT * 3072 + (h << 6);
  const u16* krb  = krope + bT * 64;
  const u16* vTb  = vT + (size_t)bh * 128 * T_;
  u16* Ps = &smem[16384 + (wid << 11)];
  const int qhi = q0 + (wid << 5) + 31;
  const int nkv = (q0 >> 6) + 2;

  for (int kv = 0; kv < nkv; ++kv){
    const int k0 = kv << 6;
    __syncthreads();                        // prior-iter LDS reads complete
    // ---- stage K (rounds 0-3) + V (rounds 4-7): 2048 x 16B chunks, swizzled sources
    #pragma unroll
    for (int r = 0; r < 8; ++r){
      int c = (r << 8) + tid;
      const u16* src;
      if (r < 4){
        int row = c >> 4, cc = c & 15;
        int ccx = (cc & 8) | ((cc & 7) ^ (row & 7));
        int col0 = ccx << 3;
        src = (col0 < 64) ? (kvPb + (size_t)(k0 + row) * 3072 + col0)
                          : (krb  + (size_t)(k0 + row) * 64 + (col0 - 64));
      } else {
        int cv = c - 1024;
        int row = cv >> 3, cc = cv & 7;
        int ccx = cc ^ (row & 7);
        src = vTb + (size_t)row * T_ + k0 + (ccx << 3);
      }
      gld_lds16(src, &smem[(size_t)((r << 8) + (wid << 6)) * 8]);
    }
    __syncthreads();                        // staged tiles visible
    if (k0 <= qhi){
      // ---- S = Q K^T
      f32x4 s[2][4] = {};
      #pragma unroll
      for (int ks = 0; ks < 4; ++ks){
        int colsw = ((ks << 5) + lk) ^ sw;
        #pragma unroll
        for (int n = 0; n < 4; ++n){
          bf16x8 kf = *reinterpret_cast<const bf16x8*>(&smem[((n << 4) + l16) * 128 + colsw]);
          s[0][n] = mfma16(qf[0][ks], kf, s[0][n]);
          s[1][n] = mfma16(qf[1][ks], kf, s[1][n]);
        }
      }
      // ---- online softmax (base-2 domain)
      #pragma unroll
      for (int rg = 0; rg < 2; ++rg){
        #pragma unroll
        for (int j = 0; j < 4; ++j){
          const int tq = q0 + (wid << 5) + (rg << 4) + r4 + j;
          float mx = -3e38f;
          #pragma unroll
          for (int n = 0; n < 4; ++n){
            int tk = k0 + (n << 4) + l16;
            float sv = s[rg][n][j] * sc2;
            sv = (tk <= tq) ? sv : -3e38f;
            s[rg][n][j] = sv;
            mx = fmaxf(mx, sv);
          }
          mx = fmaxf(mx, __shfl_xor(mx, 1));
          mx = fmaxf(mx, __shfl_xor(mx, 2));
          mx = fmaxf(mx, __shfl_xor(mx, 4));
          mx = fmaxf(mx, __shfl_xor(mx, 8));
          float mnew = fmaxf(m[rg][j], mx);
          float alpha = exp2f(m[rg][j] - mnew);
          float rs = 0.f;
          const int prow = ((rg << 4) + r4 + j) << 6;
          const int psw = ((r4 + j) & 7) << 3;
          #pragma unroll
          for (int n = 0; n < 4; ++n){
            float p = exp2f(s[rg][n][j] - mnew);
            rs += p;
            Ps[prow + (((n << 4) + l16) ^ psw)] = f2bf(p);
          }
          rs += __shfl_xor(rs, 1); rs += __shfl_xor(rs, 2);
          rs += __shfl_xor(rs, 4); rs += __shfl_xor(rs, 8);
          m[rg][j] = mnew;
          l[rg][j] = l[rg][j] * alpha + rs;
          #pragma unroll
          for (int db = 0; db < 8; ++db) o[rg][db][j] *= alpha;
        }
      }
      // ---- O += P V
      #pragma unroll
      for (int ks2 = 0; ks2 < 2; ++ks2){
        int colsw = ((ks2 << 5) + lk) ^ sw;
        bf16x8 pa0 = *reinterpret_cast<const bf16x8*>(&Ps[l16 * 64 + colsw]);
        bf16x8 pa1 = *reinterpret_cast<const bf16x8*>(&Ps[(16 + l16) * 64 + colsw]);
        #pragma unroll
        for (int db = 0; db < 8; ++db){
          bf16x8 vb = *reinterpret_cast<const bf16x8*>(&smem[8192 + ((db << 4) + l16) * 64 + colsw]);
          o[0][db] = mfma16(pa0, vb, o[0][db]);
          o[1][db] = mfma16(pa1, vb, o[1][db]);
        }
      }
    }
  }
  // ---- epilogue
  #pragma unroll
  for (int rg = 0; rg < 2; ++rg){
    #pragma unroll
    for (int j = 0; j < 4; ++j){
      float rinv = 1.f / l[rg][j];
      const int tq = q0 + (wid << 5) + (rg << 4) + r4 + j;
      u16* dst = aout + (bT + tq) * 2048 + (h << 7) + l16;
      #pragma unroll
      for (int db = 0; db < 8; ++db)
        dst[db << 4] = f2bf(o[rg][db][j] * rinv);
    }
  }
}

extern "C" void kernel_launch(void* const* d_in, const int* in_sizes, int n_in,
                              void* d_out, int out_size, void* d_ws, size_t ws_size,
                              hipStream_t stream){
  const void* x       = d_in[0];
  const void* cosp    = d_in[1];
  const void* sinp    = d_in[2];
  const void* w_kv    = d_in[3];
  const void* w_kdec  = d_in[4];
  const void* w_vdec  = d_in[5];
  const void* w_qc    = d_in[6];
  const void* w_qdec  = d_in[7];
  const void* w_krope = d_in[8];
  const void* w_qrope = d_in[9];
  const void* w_o     = d_in[10];

  char* ws = (char*)d_ws;
  size_t off = 0;
  auto alloc = [&](size_t bytes){ void* p = ws + off; off += (bytes + 255) & ~(size_t)255; return p; };
  int* flag     = (int*)alloc(256);
  u16* x_bf     = (u16*)alloc((size_t)NROWS * DIM_ * 2);
  u16* w_kvT    = (u16*)alloc((size_t)DC_ * DIM_ * 2);       // (512 x 2048)
  u16* w_kvdT   = (u16*)alloc((size_t)3072 * DC_ * 2);       // [kdecPackedT(1024); vdecT(2048)] x 512
  u16* w_qcrT   = (u16*)alloc((size_t)1664 * DIM_ * 2);      // [qcT; kropeT; qropeT] x 2048
  u16* w_qdPT   = (u16*)alloc((size_t)1024 * DCQ_ * 2);      // packed qdecT (1024 x 1536)
  u16* w_oT     = (u16*)alloc((size_t)DIM_ * DIM_ * 2);
  u16* c_kv     = (u16*)alloc((size_t)NROWS * DC_ * 2);
  u16* c_qr     = (u16*)alloc((size_t)NROWS * 1664 * 2);
  u16* qP       = (u16*)alloc((size_t)NROWS * 1024 * 2);     // packed q decode
  u16* kvP      = (u16*)alloc((size_t)NROWS * 3072 * 2);     // [kPacked(1024) | v(2048)]
  u16* krope    = (u16*)alloc((size_t)NROWS * 64 * 2);
  u16* qrope    = (u16*)alloc((size_t)NROWS * 64 * 2);
  u16* vT       = (u16*)alloc((size_t)32 * 128 * T_ * 2);    // [bh][d][t]
  u16* aout     = (u16*)alloc((size_t)NROWS * DIM_ * 2);
  (void)in_sizes; (void)n_in; (void)out_size; (void)ws_size;

  hipLaunchKernelGGL(k_detect, dim3(1), dim3(64), 0, stream, (const u16*)cosp, flag);

  int n4 = NROWS * DIM_ / 4;
  hipLaunchKernelGGL(k_conv, dim3((n4 + 255) / 256), dim3(256), 0, stream, x, x_bf, n4, flag);

  // weight transposes (grid = (dstRows/64, srcRows/64))
  hipLaunchKernelGGL(k_transpose, dim3(8,  32), dim3(256), 0, stream, w_kv,    w_kvT,                        512,  2048, 64,  flag);
  hipLaunchKernelGGL(k_transpose, dim3(16, 8),  dim3(256), 0, stream, w_kdec,  w_kvdT,                       2048, 512,  128, flag);
  hipLaunchKernelGGL(k_transpose, dim3(32, 8),  dim3(256), 0, stream, w_vdec,  w_kvdT + (size_t)1024 * 512,  2048, 512,  64,  flag);
  hipLaunchKernelGGL(k_transpose, dim3(24, 32), dim3(256), 0, stream, w_qc,    w_qcrT,                       1536, 2048, 64,  flag);
  hipLaunchKernelGGL(k_transpose, dim3(1,  32), dim3(256), 0, stream, w_krope, w_qcrT + (size_t)1536 * 2048, 64,   2048, 64,  flag);
  hipLaunchKernelGGL(k_transpose, dim3(1,  32), dim3(256), 0, stream, w_qrope, w_qcrT + (size_t)1600 * 2048, 64,   2048, 64,  flag);
  hipLaunchKernelGGL(k_transpose, dim3(16, 24), dim3(256), 0, stream, w_qdec,  w_qdPT,                       2048, 1536, 128, flag);
  hipLaunchKernelGGL(k_transpose, dim3(32, 32), dim3(256), 0, stream, w_o,     w_oT,                         2048, 2048, 64,  flag);

  // G1: c_kv = x @ w_kv            (4096 x 512,  K=2048)
  hipLaunchKernelGGL(k_gemm, dim3(NROWS/128, 512/128), dim3(256), 0, stream,
                     x_bf, DIM_, w_kvT, c_kv, DC_, NROWS, DC_, DIM_, (void*)nullptr, (const int*)nullptr);
  // G2: kvP = c_kv @ [w_kdecP | w_vdec]   (4096 x 3072, K=512)
  hipLaunchKernelGGL(k_gemm, dim3(NROWS/128, 3072/128), dim3(256), 0, stream,
                     c_kv, DC_, w_kvdT, kvP, 3072, NROWS, 3072, DC_, (void*)nullptr, (const int*)nullptr);
  // G3: c_qr = x @ [w_qc | w_krope | w_qrope] (4096 x 1664, K=2048)
  hipLaunchKernelGGL(k_gemm, dim3(NROWS/128, 1664/128), dim3(256), 0, stream,
                     x_bf, DIM_, w_qcrT, c_qr, 1664, NROWS, 1664, DIM_, (void*)nullptr, (const int*)nullptr);
  // G4: qP = c_qr[:, :1536] @ w_qdecP   (4096 x 1024, K=1536)
  hipLaunchKernelGGL(k_gemm, dim3(NROWS/128, 1024/128), dim3(256), 0, stream,
                     c_qr, 1664, w_qdPT, qP, 1024, NROWS, 1024, DCQ_, (void*)nullptr, (const int*)nullptr);
  // RoPE
  hipLaunchKernelGGL(k_rope, dim3(NROWS * 128 / 256), dim3(256), 0, stream,
                     c_qr + 1536, cosp, sinp, flag, krope, qrope);
  // vT[bh][d][t]
  hipLaunchKernelGGL(k_vt, dim3(T_/64, 2, 32), dim3(256), 0, stream, kvP, vT);
  // attention
  hipLaunchKernelGGL(k_attn, dim3(16, 32), dim3(256), 0, stream,
                     qP, kvP, vT, krope, qrope, aout);
  // G5: out = aout @ w_o  (writes d_out; dtype per flag)
  hipLaunchKernelGGL(k_gemm, dim3(NROWS/128, DIM_/128), dim3(256), 0, stream,
                     aout, DIM_, w_oT, (u16*)nullptr, DIM_, NROWS, DIM_, DIM_, d_out, (const int*)flag);
}

// Round 3
// 420.539 us; speedup vs baseline: 1.5614x; 1.0209x over previous
//
#include <hip/hip_runtime.h>
#include <stdint.h>
#include <math.h>

#define B_    2
#define T_    2048
#define DIM_  2048
#define H_    16
#define DC_   512
#define DCQ_  1536
#define NROWS (B_*T_)   // 4096
#define NITEMS 512

typedef unsigned short u16;
typedef __attribute__((ext_vector_type(8))) __bf16 bf16x8;
typedef __attribute__((ext_vector_type(4))) float  f32x4;
typedef __attribute__((ext_vector_type(8))) unsigned short u16x8;
typedef __attribute__((ext_vector_type(4))) float  f4v;

__device__ __forceinline__ u16 f2bf(float f){
  unsigned u = __float_as_uint(f);
  u += 0x7FFFu + ((u >> 16) & 1u);   // RNE
  return (u16)(u >> 16);
}
__device__ __forceinline__ float bf2f(u16 h){ return __uint_as_float(((unsigned)h) << 16); }

// async global->LDS, 16B per lane; LDS dest = wave-uniform base + lane*16.
__device__ __forceinline__ void gld_lds16(const void* g, void* l){
  auto gp = reinterpret_cast<__attribute__((address_space(1))) unsigned int*>(
      reinterpret_cast<uintptr_t>(g));
  auto lp = reinterpret_cast<__attribute__((address_space(3))) unsigned int*>(
      reinterpret_cast<uintptr_t>(l));
  __builtin_amdgcn_global_load_lds(gp, lp, 16, 0, 0);
}

__device__ __forceinline__ f32x4 mfma16(bf16x8 a, bf16x8 b, f32x4 c){
  return __builtin_amdgcn_mfma_f32_16x16x32_bf16(a, b, c, 0, 0, 0);
}

// ---------------- dtype detect + ticket reset
__global__ void k_detect(const u16* cosr, int* flag, int* ticket){
  if (threadIdx.x == 0){
    *flag = (cosr[0] == (u16)0x3F80u) ? 1 : 0;
    *ticket = 0;
  }
}

// ---------------- convert to bf16
__global__ void k_conv(const void* __restrict__ src, u16* __restrict__ dst, int n4, const int* flag){
  int id = blockIdx.x * 256 + threadIdx.x;
  if (id >= n4) return;
  if (*flag){
    reinterpret_cast<uint2*>(dst)[id] = reinterpret_cast<const uint2*>(src)[id];
  } else {
    f4v v = reinterpret_cast<const f4v*>(src)[id];
    unsigned lo = (unsigned)f2bf(v.x) | ((unsigned)f2bf(v.y) << 16);
    unsigned hi = (unsigned)f2bf(v.z) | ((unsigned)f2bf(v.w) << 16);
    reinterpret_cast<uint2*>(dst)[id] = make_uint2(lo, hi);
  }
}

// ---------------- transpose+convert to bf16 with optional column packing.
__global__ void k_transpose(const void* __restrict__ src, u16* __restrict__ dst,
                            int srcStride, int dstStride, int cblk, const int* flag){
  __shared__ u16 tile[64][72];
  const int r0 = blockIdx.y << 6, c0 = blockIdx.x * cblk;
  const int tid = threadIdx.x;
  const int f = *flag;
  #pragma unroll
  for (int i = 0; i < 2; ++i){
    int task = (i << 8) + tid;
    int r = task >> 3, c8 = (task & 7) << 3;
    if (f){
      const u16* p = (const u16*)src + (size_t)(r0 + r) * srcStride + c0 + c8;
      u16x8 v = *reinterpret_cast<const u16x8*>(p);
      #pragma unroll
      for (int j = 0; j < 8; ++j) tile[r][c8 + j] = v[j];
    } else {
      const float* p = (const float*)src + (size_t)(r0 + r) * srcStride + c0 + c8;
      f4v a = reinterpret_cast<const f4v*>(p)[0];
      f4v b = reinterpret_cast<const f4v*>(p)[1];
      tile[r][c8+0]=f2bf(a.x); tile[r][c8+1]=f2bf(a.y); tile[r][c8+2]=f2bf(a.z); tile[r][c8+3]=f2bf(a.w);
      tile[r][c8+4]=f2bf(b.x); tile[r][c8+5]=f2bf(b.y); tile[r][c8+6]=f2bf(b.z); tile[r][c8+7]=f2bf(b.w);
    }
  }
  __syncthreads();
  #pragma unroll
  for (int i = 0; i < 2; ++i){
    int task = (i << 8) + tid;
    int rr = task >> 3, cc8 = (task & 7) << 3;
    u16x8 v;
    #pragma unroll
    for (int j = 0; j < 8; ++j) v[j] = tile[cc8 + j][rr];
    *reinterpret_cast<u16x8*>(dst + (size_t)((blockIdx.x << 6) + rr) * dstStride + r0 + cc8) = v;
  }
}

// ---------------- build vT[bh][d][t] from kvP cols 1024 + h*128 + d
__global__ void k_vt(const u16* __restrict__ kvP, u16* __restrict__ vT){
  __shared__ u16 tile[64][72];
  const int t0 = blockIdx.x << 6, d0 = blockIdx.y << 6, bh = blockIdx.z;
  const int b = bh >> 4, h = bh & 15;
  const int tid = threadIdx.x;
  #pragma unroll
  for (int i = 0; i < 2; ++i){
    int task = (i << 8) + tid;
    int r = task >> 3, c8 = (task & 7) << 3;
    const u16* p = kvP + (size_t)(b * T_ + t0 + r) * 3072 + 1024 + h * 128 + d0 + c8;
    u16x8 v = *reinterpret_cast<const u16x8*>(p);
    #pragma unroll
    for (int j = 0; j < 8; ++j) tile[r][c8 + j] = v[j];
  }
  __syncthreads();
  #pragma unroll
  for (int i = 0; i < 2; ++i){
    int task = (i << 8) + tid;
    int rr = task >> 3, cc8 = (task & 7) << 3;
    u16x8 v;
    #pragma unroll
    for (int j = 0; j < 8; ++j) v[j] = tile[cc8 + j][rr];
    *reinterpret_cast<u16x8*>(vT + ((size_t)bh * 128 + d0 + rr) * T_ + t0 + cc8) = v;
  }
}

// ---------------- GEMM: C(MxN) = A(MxK, lda) * Bt(NxK row-major)  [bf16 in, fp32 acc]
__global__ __launch_bounds__(256) void k_gemm(const u16* __restrict__ A, int lda,
                                              const u16* __restrict__ Bt,
                                              u16* __restrict__ C, int ldc,
                                              int M, int N, int K,
                                              void* outp, const int* flag){
  __shared__ alignas(16) u16 As[128 * 64];
  __shared__ alignas(16) u16 Bs[128 * 64];
  const int tid = threadIdx.x;
  const int wid = tid >> 6, lane = tid & 63;
  const int m0 = blockIdx.x << 7, n0 = blockIdx.y << 7;
  const int wr = wid >> 1, wc = wid & 1;
  const int l16 = lane & 15, lk = (lane >> 4) << 3;
  const int srow = tid >> 3, scol = (tid & 7) << 3;
  f32x4 acc[4][4] = {};
  const int nkt = K >> 6;
  for (int kt = 0; kt < nkt; ++kt){
    const int kb = kt << 6;
    #pragma unroll
    for (int i = 0; i < 4; ++i){
      int r = (i << 5) + srow;
      gld_lds16(A  + (size_t)(m0 + r) * lda + kb + scol, &As[(i << 11) + (wid << 9)]);
      gld_lds16(Bt + (size_t)(n0 + r) * K   + kb + scol, &Bs[(i << 11) + (wid << 9)]);
    }
    __syncthreads();
    #pragma unroll
    for (int ks = 0; ks < 2; ++ks){
      bf16x8 af[4], bfr[4];
      #pragma unroll
      for (int mi = 0; mi < 4; ++mi)
        af[mi] = *reinterpret_cast<const bf16x8*>(&As[((wr << 6) + (mi << 4) + l16) * 64 + (ks << 5) + lk]);
      #pragma unroll
      for (int ni = 0; ni < 4; ++ni)
        bfr[ni] = *reinterpret_cast<const bf16x8*>(&Bs[((wc << 6) + (ni << 4) + l16) * 64 + (ks << 5) + lk]);
      #pragma unroll
      for (int mi = 0; mi < 4; ++mi)
        #pragma unroll
        for (int ni = 0; ni < 4; ++ni)
          acc[mi][ni] = mfma16(af[mi], bfr[ni], acc[mi][ni]);
    }
    __syncthreads();
  }
  const int r4 = (lane >> 4) << 2;
  const int f = flag ? *flag : 1;
  #pragma unroll
  for (int mi = 0; mi < 4; ++mi){
    int row = m0 + (wr << 6) + (mi << 4) + r4;
    #pragma unroll
    for (int ni = 0; ni < 4; ++ni){
      int col = n0 + (wc << 6) + (ni << 4) + l16;
      #pragma unroll
      for (int j = 0; j < 4; ++j){
        float v = acc[mi][ni][j];
        if (outp){
          if (f) ((u16*)outp)[(size_t)(row + j) * ldc + col] = f2bf(v);
          else   ((float*)outp)[(size_t)(row + j) * ldc + col] = v;
        } else {
          C[(size_t)(row + j) * ldc + col] = f2bf(v);
        }
      }
    }
  }
}

// ---------------- RoPE from xc cols 2048..2175 (stride 2176)
__global__ void k_rope(const u16* __restrict__ ropes, const void* __restrict__ cosp,
                       const void* __restrict__ sinp, const int* flag,
                       u16* __restrict__ krope, u16* __restrict__ qrope){
  int id = blockIdx.x * 256 + threadIdx.x;
  if (id >= NROWS * 128) return;
  int row = id >> 7, c = id & 127;
  int t = row & (T_ - 1);
  int d = c & 63, i = d & 31;
  float cs, sn;
  if (*flag){ cs = bf2f(((const u16*)cosp)[t * 32 + i]); sn = bf2f(((const u16*)sinp)[t * 32 + i]); }
  else      { cs = ((const float*)cosp)[t * 32 + i];     sn = ((const float*)sinp)[t * 32 + i]; }
  int base = c & 64;
  float t1 = bf2f(ropes[(size_t)row * 2176 + base + i]);
  float t2 = bf2f(ropes[(size_t)row * 2176 + base + 32 + i]);
  float v = (d < 32) ? (t1 * cs - t2 * sn) : (t2 * cs + t1 * sn);
  ((c < 64) ? krope : qrope)[(size_t)row * 64 + d] = f2bf(v);
}

// ---------------- causal flash attention, persistent blocks + ticket.
// Item = (qt, bh): 128 q-rows, 4 waves x 32 rows. KV tiles of 64, double-buffered.
// LDS per buffer b (32KB): Ks [64][128] @ b*16384, Vs [128][64] @ b*16384+8192 (u16 idx).
// Ps [32][64] per wave @ 32768 + wid*2048. All XOR-swizzled (col ^= (row&7)<<3).
__global__ __launch_bounds__(256, 2) void k_attn(const u16* __restrict__ qP,
                                                 const u16* __restrict__ kvP,
                                                 const u16* __restrict__ vT,
                                                 const u16* __restrict__ krope,
                                                 const u16* __restrict__ qrope,
                                                 u16* __restrict__ aout,
                                                 int* __restrict__ ticket){
  __shared__ alignas(16) u16 smem[40960];   // 80 KB
  __shared__ int s_item;
  const int tid = threadIdx.x, wid = tid >> 6, lane = tid & 63;
  const int l16 = lane & 15, g = lane >> 4;
  const int lk = g << 3, r4 = g << 2;
  const float sc2 = 0.08838834764831845f * 1.4426950408889634f;   // 1/sqrt(128)*log2e
  u16* Ps = &smem[32768 + (wid << 11)];

  // staging source precompute (per-thread swizzled chunk coords)
  // K rounds r=0..3: chunk c = r*256+tid -> row=c>>4, cc=c&15, ccx=(cc&8)|((cc&7)^(row&7))
  // V rounds r=4..7: cv = c-1024 -> row=cv>>3, cc=cv&7, ccx=cc^(row&7)

  while (true){
    if (tid == 0) s_item = atomicAdd(ticket, 1);
    __syncthreads();
    const int it = s_item;
    if (it >= NITEMS) break;
    const int qt = 15 - (it >> 5);          // heavy-first
    const int bh = it & 31, b = bh >> 4, h = bh & 15;
    const int q0 = qt << 7;
    const size_t bT = (size_t)b * T_;
    const u16* kvPb = kvP + bT * 3072 + (h << 6);
    const u16* krb  = krope + bT * 64;
    const u16* vTb  = vT + (size_t)bh * 128 * T_;
    const int qhi = q0 + (wid << 5) + 31;
    const int nkv = (q0 >> 6) + 2;

    auto STAGE = [&](int buf, int k0){
      const int base = buf << 14;           // u16 idx (32KB per buffer)
      #pragma unroll
      for (int r = 0; r < 8; ++r){
        int c = (r << 8) + tid;
        const u16* src;
        if (r < 4){
          int row = c >> 4, cc = c & 15;
          int ccx = (cc & 8) | ((cc & 7) ^ (row & 7));
          int col0 = ccx << 3;
          src = (col0 < 64) ? (kvPb + (size_t)(k0 + row) * 3072 + col0)
                            : (krb  + (size_t)(k0 + row) * 64 + (col0 - 64));
        } else {
          int cv = c - 1024;
          int row = cv >> 3, cc = cv & 7;
          int ccx = cc ^ (row & 7);
          src = vTb + (size_t)row * T_ + k0 + (ccx << 3);
        }
        gld_lds16(src, &smem[base + (((r << 8) + (wid << 6)) << 3)]);
      }
    };

    // Q fragments
    bf16x8 qf[2][4];
    #pragma unroll
    for (int rg = 0; rg < 2; ++rg){
      size_t grow = bT + q0 + (wid << 5) + (rg << 4) + l16;
      #pragma unroll
      for (int ks = 0; ks < 4; ++ks){
        int d = (ks << 5) + lk;
        const u16* src = (ks < 2) ? (qP + grow * 1024 + (h << 6) + d)
                                  : (qrope + grow * 64 + (d - 64));
        qf[rg][ks] = *reinterpret_cast<const bf16x8*>(src);
      }
    }
    f32x4 o[2][8] = {};
    float m[2][4], l[2][4];
    #pragma unroll
    for (int rg = 0; rg < 2; ++rg)
      #pragma unroll
      for (int j = 0; j < 4; ++j){ m[rg][j] = -3e38f; l[rg][j] = 0.f; }

    STAGE(0, 0);
    __syncthreads();                        // tile 0 resident; also fences s_item
    int cur = 0;

    for (int kv = 0; kv < nkv; ++kv){
      const int k0 = kv << 6;
      if (kv + 1 < nkv) STAGE(cur ^ 1, (kv + 1) << 6);   // prefetch next tile
      if (k0 <= qhi){
        const int kb = cur << 14;
        // ---- S = Q K^T
        f32x4 s[2][4] = {};
        #pragma unroll
        for (int ks = 0; ks < 4; ++ks){
          int colsw = ((ks << 5) + lk) ^ ((l16 & 7) << 3);
          #pragma unroll
          for (int n = 0; n < 4; ++n){
            bf16x8 kf = *reinterpret_cast<const bf16x8*>(&smem[kb + ((n << 4) + l16) * 128 + colsw]);
            s[0][n] = mfma16(qf[0][ks], kf, s[0][n]);
            s[1][n] = mfma16(qf[1][ks], kf, s[1][n]);
          }
        }
        // ---- scale + mask + row max
        float mx8[2][4];
        bool grow_ = false;
        #pragma unroll
        for (int rg = 0; rg < 2; ++rg){
          #pragma unroll
          for (int j = 0; j < 4; ++j){
            const int tq = q0 + (wid << 5) + (rg << 4) + r4 + j;
            float mx = -3e38f;
            #pragma unroll
            for (int n = 0; n < 4; ++n){
              int tk = k0 + (n << 4) + l16;
              float sv = s[rg][n][j] * sc2;
              sv = (tk <= tq) ? sv : -3e38f;
              s[rg][n][j] = sv;
              mx = fmaxf(mx, sv);
            }
            mx = fmaxf(mx, __shfl_xor(mx, 1));
            mx = fmaxf(mx, __shfl_xor(mx, 2));
            mx = fmaxf(mx, __shfl_xor(mx, 4));
            mx = fmaxf(mx, __shfl_xor(mx, 8));
            mx8[rg][j] = mx;
            grow_ |= (mx > m[rg][j] + 8.f);
          }
        }
        // ---- deferred rescale (wave-uniform branch)
        if (__ballot(grow_)){
          #pragma unroll
          for (int rg = 0; rg < 2; ++rg)
            #pragma unroll
            for (int j = 0; j < 4; ++j){
              float mnew = fmaxf(m[rg][j], mx8[rg][j]);
              float alpha = exp2f(m[rg][j] - mnew);
              m[rg][j] = mnew;
              l[rg][j] *= alpha;
              #pragma unroll
              for (int db = 0; db < 8; ++db) o[rg][db][j] *= alpha;
            }
        }
        // ---- P = exp2(s - m), row sums, store P
        #pragma unroll
        for (int rg = 0; rg < 2; ++rg){
          #pragma unroll
          for (int j = 0; j < 4; ++j){
            float rs = 0.f;
            const int prow = ((rg << 4) + r4 + j) << 6;
            const int psw = ((r4 + j) & 7) << 3;
            #pragma unroll
            for (int n = 0; n < 4; ++n){
              float p = exp2f(s[rg][n][j] - m[rg][j]);
              rs += p;
              Ps[prow + (((n << 4) + l16) ^ psw)] = f2bf(p);
            }
            rs += __shfl_xor(rs, 1); rs += __shfl_xor(rs, 2);
            rs += __shfl_xor(rs, 4); rs += __shfl_xor(rs, 8);
            l[rg][j] += rs;
          }
        }
        // ---- O += P V
        #pragma unroll
        for (int ks2 = 0; ks2 < 2; ++ks2){
          int colsw = ((ks2 << 5) + lk) ^ ((l16 & 7) << 3);
          bf16x8 pa0 = *reinterpret_cast<const bf16x8*>(&Ps[l16 * 64 + colsw]);
          bf16x8 pa1 = *reinterpret_cast<const bf16x8*>(&Ps[(16 + l16) * 64 + colsw]);
          #pragma unroll
          for (int db = 0; db < 8; ++db){
            bf16x8 vb = *reinterpret_cast<const bf16x8*>(&smem[kb + 8192 + ((db << 4) + l16) * 64 + colsw]);
            o[0][db] = mfma16(pa0, vb, o[0][db]);
            o[1][db] = mfma16(pa1, vb, o[1][db]);
          }
        }
      }
      __syncthreads();                      // drains prefetch; LDS reads done before reuse
      cur ^= 1;
    }
    // ---- epilogue
    #pragma unroll
    for (int rg = 0; rg < 2; ++rg){
      #pragma unroll
      for (int j = 0; j < 4; ++j){
        float rinv = 1.f / l[rg][j];
        const int tq = q0 + (wid << 5) + (rg << 4) + r4 + j;
        u16* dst = aout + (bT + tq) * 2048 + (h << 7) + l16;
        #pragma unroll
        for (int db = 0; db < 8; ++db)
          dst[db << 4] = f2bf(o[rg][db][j] * rinv);
      }
    }
  }
}

extern "C" void kernel_launch(void* const* d_in, const int* in_sizes, int n_in,
                              void* d_out, int out_size, void* d_ws, size_t ws_size,
                              hipStream_t stream){
  const void* x       = d_in[0];
  const void* cosp    = d_in[1];
  const void* sinp    = d_in[2];
  const void* w_kv    = d_in[3];
  const void* w_kdec  = d_in[4];
  const void* w_vdec  = d_in[5];
  const void* w_qc    = d_in[6];
  const void* w_qdec  = d_in[7];
  const void* w_krope = d_in[8];
  const void* w_qrope = d_in[9];
  const void* w_o     = d_in[10];

  char* ws = (char*)d_ws;
  size_t off = 0;
  auto alloc = [&](size_t bytes){ void* p = ws + off; off += (bytes + 255) & ~(size_t)255; return p; };
  int* flag     = (int*)alloc(256);
  int* ticket   = (int*)alloc(256);
  u16* x_bf     = (u16*)alloc((size_t)NROWS * DIM_ * 2);
  u16* w_c1T    = (u16*)alloc((size_t)2176 * DIM_ * 2);      // [kvT(512); qcT(1536); kropeT(64); qropeT(64)] x 2048
  u16* w_kvdT   = (u16*)alloc((size_t)3072 * DC_ * 2);       // [kdecPackedT(1024); vdecT(2048)] x 512
  u16* w_qdPT   = (u16*)alloc((size_t)1024 * DCQ_ * 2);      // packed qdecT (1024 x 1536)
  u16* w_oT     = (u16*)alloc((size_t)DIM_ * DIM_ * 2);
  u16* xc       = (u16*)alloc((size_t)NROWS * 2176 * 2);     // [c_kv(512) | c_q(1536) | ropes(128)]
  u16* qP       = (u16*)alloc((size_t)NROWS * 1024 * 2);     // packed q decode
  u16* kvP      = (u16*)alloc((size_t)NROWS * 3072 * 2);     // [kPacked(1024) | v(2048)]
  u16* krope    = (u16*)alloc((size_t)NROWS * 64 * 2);
  u16* qrope    = (u16*)alloc((size_t)NROWS * 64 * 2);
  u16* vT       = (u16*)alloc((size_t)32 * 128 * T_ * 2);    // [bh][d][t]
  u16* aout     = (u16*)alloc((size_t)NROWS * DIM_ * 2);
  (void)in_sizes; (void)n_in; (void)out_size; (void)ws_size;

  hipLaunchKernelGGL(k_detect, dim3(1), dim3(64), 0, stream, (const u16*)cosp, flag, ticket);

  int n4 = NROWS * DIM_ / 4;
  hipLaunchKernelGGL(k_conv, dim3((n4 + 255) / 256), dim3(256), 0, stream, x, x_bf, n4, flag);

  // weight transposes into combined buffers (grid = (dstRows/64, srcRows/64))
  hipLaunchKernelGGL(k_transpose, dim3(8,  32), dim3(256), 0, stream, w_kv,    w_c1T,                        512,  2048, 64,  flag);
  hipLaunchKernelGGL(k_transpose, dim3(24, 32), dim3(256), 0, stream, w_qc,    w_c1T + (size_t)512 * 2048,   1536, 2048, 64,  flag);
  hipLaunchKernelGGL(k_transpose, dim3(1,  32), dim3(256), 0, stream, w_krope, w_c1T + (size_t)2048 * 2048,  64,   2048, 64,  flag);
  hipLaunchKernelGGL(k_transpose, dim3(1,  32), dim3(256), 0, stream, w_qrope, w_c1T + (size_t)2112 * 2048,  64,   2048, 64,  flag);
  hipLaunchKernelGGL(k_transpose, dim3(16, 8),  dim3(256), 0, stream, w_kdec,  w_kvdT,                       2048, 512,  128, flag);
  hipLaunchKernelGGL(k_transpose, dim3(32, 8),  dim3(256), 0, stream, w_vdec,  w_kvdT + (size_t)1024 * 512,  2048, 512,  64,  flag);
  hipLaunchKernelGGL(k_transpose, dim3(16, 24), dim3(256), 0, stream, w_qdec,  w_qdPT,                       2048, 1536, 128, flag);
  hipLaunchKernelGGL(k_transpose, dim3(32, 32), dim3(256), 0, stream, w_o,     w_oT,                         2048, 2048, 64,  flag);

  // G13: xc = x @ [w_kv | w_qc | w_krope | w_qrope]  (4096 x 2176, K=2048)
  hipLaunchKernelGGL(k_gemm, dim3(NROWS/128, 2176/128), dim3(256), 0, stream,
                     x_bf, DIM_, w_c1T, xc, 2176, NROWS, 2176, DIM_, (void*)nullptr, (const int*)nullptr);
  // G2: kvP = xc[:, :512] @ [w_kdecP | w_vdec]   (4096 x 3072, K=512)
  hipLaunchKernelGGL(k_gemm, dim3(NROWS/128, 3072/128), dim3(256), 0, stream,
                     xc, 2176, w_kvdT, kvP, 3072, NROWS, 3072, DC_, (void*)nullptr, (const int*)nullptr);
  // G4: qP = xc[:, 512:2048] @ w_qdecP   (4096 x 1024, K=1536)
  hipLaunchKernelGGL(k_gemm, dim3(NROWS/128, 1024/128), dim3(256), 0, stream,
                     xc + 512, 2176, w_qdPT, qP, 1024, NROWS, 1024, DCQ_, (void*)nullptr, (const int*)nullptr);
  // RoPE
  hipLaunchKernelGGL(k_rope, dim3(NROWS * 128 / 256), dim3(256), 0, stream,
                     xc + 2048, cosp, sinp, flag, krope, qrope);
  // vT[bh][d][t]
  hipLaunchKernelGGL(k_vt, dim3(T_/64, 2, 32), dim3(256), 0, stream, kvP, vT);
  // attention (persistent, 512 worker blocks)
  hipLaunchKernelGGL(k_attn, dim3(512), dim3(256), 0, stream,
                     qP, kvP, vT, krope, qrope, aout, ticket);
  // G5: out = aout @ w_o  (writes d_out; dtype per flag)
  hipLaunchKernelGGL(k_gemm, dim3(NROWS/128, DIM_/128), dim3(256), 0, stream,
                     aout, DIM_, w_oT, (u16*)nullptr, DIM_, NROWS, DIM_, DIM_, d_out, (const int*)flag);
}